// Round 11
// baseline (4225.743 us; speedup 1.0000x reference)
//
#include <hip/hip_runtime.h>
#include <cstddef>

#define T_STEPS 1024
#define NB      64
#define DIN     128
#define HID     256

typedef unsigned short u16;
typedef unsigned int   u32;
typedef unsigned long long u64;
typedef __attribute__((ext_vector_type(8))) short short8;
typedef __attribute__((ext_vector_type(4))) float f32x4;

// ws byte offsets
#define WG_OFF   0u          // bf16 weights [2][1024 rows j*4+q][384 k] = 1,572,864 B
#define BIAS_OFF 1572864u    // f32 [2][1024]
#define XB_OFF   1581056u    // bf16 x [1024][64][128] = 16,777,216 B
#define HB_OFF   18358272u   // u32 hbuf [4 slot][8 grp][16 b][256 j] = 524,288 B

#define OUT_MAIN (T_STEPS * NB * 2 * HID)
#define TAIL_H   OUT_MAIN
#define TAIL_C   (OUT_MAIN + 2 * NB * HID)

__device__ __forceinline__ u16 f2bf(float f) {
  unsigned u = __float_as_uint(f);
  return (u16)((u + 0x7fffu + ((u >> 16) & 1u)) >> 16);  // RNE
}
__device__ __forceinline__ float sigm(float v) { return 1.f / (1.f + __expf(-v)); }
__device__ __forceinline__ float tanh_fast(float x) {
  float e = __expf(-2.f * fabsf(x));
  float r = (1.f - e) / (1.f + e);
  return x < 0.f ? -r : r;
}

__global__ void prep_kernel(const float* __restrict__ x,
                            const float* __restrict__ Wih_f, const float* __restrict__ Whh_f,
                            const float* __restrict__ bih_f, const float* __restrict__ bhh_f,
                            const float* __restrict__ Wih_r, const float* __restrict__ Whh_r,
                            const float* __restrict__ bih_r, const float* __restrict__ bhh_r,
                            const float* __restrict__ hx,
                            u16* __restrict__ Wg, float* __restrict__ bias4,
                            u16* __restrict__ xb, u32* __restrict__ hbuf) {
  // segments: W 786432 | bias 2048 | xb 8388608 | hbuf 131072
  const int total = 786432 + 2048 + 8388608 + 131072;
  for (int i = blockIdx.x * blockDim.x + threadIdx.x; i < total;
       i += gridDim.x * blockDim.x) {
    if (i < 786432) {
      int d = i / 393216;
      int r = i - d * 393216;
      int rowg = r / 384, k = r - rowg * 384;   // rowg = j*4+q interleaved
      int j = rowg >> 2, q = rowg & 3;
      int g = q * HID + j;                      // torch gate row
      const float* Wih = d ? Wih_r : Wih_f;
      const float* Whh = d ? Whh_r : Whh_f;
      float v = (k < DIN) ? Wih[g * DIN + k] : Whh[g * HID + (k - DIN)];
      Wg[i] = f2bf(v);
    } else if (i < 786432 + 2048) {
      int r = i - 786432;
      int d = r >> 10, rowg = r & 1023;
      int j = rowg >> 2, q = rowg & 3;
      int g = q * HID + j;
      bias4[r] = d ? (bih_r[g] + bhh_r[g]) : (bih_f[g] + bhh_f[g]);
    } else if (i < 786432 + 2048 + 8388608) {
      int r = i - (786432 + 2048);
      xb[r] = f2bf(x[r]);                       // [t][b][k]
    } else {
      int r = i - (786432 + 2048 + 8388608);    // hbuf cell index
      int slot = r >> 15;
      int rem  = r & 32767;
      int grp = rem >> 12, bb = (rem >> 8) & 15, j = r & 255;
      if (slot == 3) {                          // read-slot for s=0, tag 1
        int d = grp >> 2, b = (grp & 3) * 16 + bb;
        hbuf[r] = (1u << 16) | f2bf(hx[((size_t)d * NB + b) * HID + j]);
      } else {
        hbuf[r] = 0u;
      }
    }
  }
}

#define MFMA __builtin_amdgcn_mfma_f32_16x16x32_bf16
#define ALD64(P) __hip_atomic_load((P), __ATOMIC_RELAXED, __HIP_MEMORY_SCOPE_AGENT)
#define CHK(V, E) if ((((u32)((V) >> 16) & 0xffffu) != wt) || \
                      (((u32)((V) >> 48) & 0xffffu) != wt)) { \
    V = ALD64(cbp + (E)); bad = true; }

// 128 WGs x 256 thr. grp = bid&7 (16 WGs co-XCD under round-robin), jsl = bid>>3.
// grp = d*4 + btile. Per WG: 64 gate rows, 16 batches (full MFMA A-tile).
// Weights in LDS. Exchange: tagged u32 cells (flag==data, 1 LLC RT), depth-4
// slots (provably no overwrite-before-read). 2 barriers/step, no vmcnt drains.
__global__ __launch_bounds__(256, 1) void lstm_tag4(
    const u16* __restrict__ Wg, const float* __restrict__ bias4,
    const u16* __restrict__ xb, const float* __restrict__ cx,
    u32* __restrict__ hbuf, float* __restrict__ out) {
  extern __shared__ char smem[];
  u16* wl   = (u16*)smem;                 // [64][392]    50,176 B
  u16* xsh  = (u16*)(smem + 50176);       // [2][16][136]  8,704 B
  u16* hsh  = (u16*)(smem + 58880);       // [16][264]     8,448 B
  float* gl = (float*)(smem + 67328);     // [4 wave][16 m][20]  5,120 B (tot 72,448)

  const int tid = threadIdx.x;
  const int bid = blockIdx.x;
  const int grp = bid & 7;
  const int jsl = bid >> 3;
  const int d = grp >> 2, b0 = (grp & 3) * 16;
  const int w = tid >> 6, l = tid & 63;

  // one-time: weight slice -> LDS
  {
    const u32* src = (const u32*)(Wg + (size_t)(d * 1024 + jsl * 64) * 384);
    u32* dst = (u32*)wl;
    for (int iu = tid; iu < 64 * 192; iu += 256) {
      int r = iu / 192, c = iu - r * 192;
      dst[r * 196 + c] = src[iu];
    }
  }
  const float bv = bias4[d * 1024 + jsl * 64 + w * 16 + (l & 15)];

  // elementwise identity: wave w owns j-slots [w*4, w*4+4): eb = l>>2, ejl = l&3
  const int eb = l >> 2, ejl = l & 3;
  const int jglob = jsl * 16 + w * 4 + ejl;
  float c_reg = cx[((size_t)d * NB + b0 + eb) * HID + jglob];
  float* glw = gl + w * 320;              // per-wave slab [16 m][20]

  const int xr_row = tid >> 4;            // x stage row
  const int xc = (tid & 15) * 8;          // 8 u16 = 16 B
  const int pb = tid >> 4;                // h consumer batch
  const int js = tid & 15;                // producer WG (j-slice) this thread polls
  const int cj0 = js * 16;                // 16 h cells

  // prologue: stage x(t0), prefetch x(t1)
  { int t0 = d ? 1023 : 0;
    *(uint4*)&xsh[(0 * 16 + xr_row) * 136 + xc] =
        *(const uint4*)&xb[((size_t)t0 * NB + b0 + xr_row) * DIN + xc]; }
  uint4 xv;
  { int t1 = d ? 1022 : 1;
    xv = *(const uint4*)&xb[((size_t)t1 * NB + b0 + xr_row) * DIN + xc]; }
  __syncthreads();

  for (int s = 0; s < T_STEPS; ++s) {
    const int t = d ? (1023 - s) : s;
    const int xp = s & 1;
    const int sr = (s + 3) & 3;           // read slot
    const int sw = s & 3;                 // write slot
    const u32 wt = (u32)(s + 1) & 0xffffu;

    // 1. issue tagged-cell polls (8 u64 = 16 cells)
    const u64* cbp = (const u64*)(hbuf + (((size_t)(sr * 8 + grp)) * 16 + pb) * 256 + cj0);
    u64 v0 = ALD64(cbp + 0), v1 = ALD64(cbp + 1), v2 = ALD64(cbp + 2), v3 = ALD64(cbp + 3);
    u64 v4 = ALD64(cbp + 4), v5 = ALD64(cbp + 5), v6 = ALD64(cbp + 6), v7 = ALD64(cbp + 7);

    // 2. park x(s+1) into the other x buffer
    if (s < 1023) *(uint4*)&xsh[((xp ^ 1) * 16 + xr_row) * 136 + xc] = xv;

    // 3. x-part MFMA (hides poll round trip); two acc chains
    f32x4 acc0 = {bv, bv, bv, bv}, acc1 = {0.f, 0.f, 0.f, 0.f};
    {
      const u16* xr = &xsh[(xp * 16 + (l & 15)) * 136 + (l >> 4) * 8];
      const u16* wr = wl + (size_t)(w * 16 + (l & 15)) * 392 + (l >> 4) * 8;
      acc0 = MFMA(*(const short8*)(xr + 0),  *(const short8*)(wr + 0),  acc0, 0, 0, 0);
      acc1 = MFMA(*(const short8*)(xr + 32), *(const short8*)(wr + 32), acc1, 0, 0, 0);
      acc0 = MFMA(*(const short8*)(xr + 64), *(const short8*)(wr + 64), acc0, 0, 0, 0);
      acc1 = MFMA(*(const short8*)(xr + 96), *(const short8*)(wr + 96), acc1, 0, 0, 0);
    }
    // 4. x global prefetch for s+2
    if (s < 1022) {
      int tn = d ? (1021 - s) : (s + 2);
      xv = *(const uint4*)&xb[((size_t)tn * NB + b0 + xr_row) * DIN + xc];
    }

    // 5. finish polls (reload only stale u64s; each round = 1 LLC RT)
    {
      bool bad = true;
      while (bad) {
        bad = false;
        CHK(v0, 0) CHK(v1, 1) CHK(v2, 2) CHK(v3, 3)
        CHK(v4, 4) CHK(v5, 5) CHK(v6, 6) CHK(v7, 7)
      }
    }
    // 6. extract payloads -> hsh
    {
      uint4 H0, H1;
      H0.x = (u32)(u16)v0 | ((u32)(u16)(v0 >> 32) << 16);
      H0.y = (u32)(u16)v1 | ((u32)(u16)(v1 >> 32) << 16);
      H0.z = (u32)(u16)v2 | ((u32)(u16)(v2 >> 32) << 16);
      H0.w = (u32)(u16)v3 | ((u32)(u16)(v3 >> 32) << 16);
      H1.x = (u32)(u16)v4 | ((u32)(u16)(v4 >> 32) << 16);
      H1.y = (u32)(u16)v5 | ((u32)(u16)(v5 >> 32) << 16);
      H1.z = (u32)(u16)v6 | ((u32)(u16)(v6 >> 32) << 16);
      H1.w = (u32)(u16)v7 | ((u32)(u16)(v7 >> 32) << 16);
      *(uint4*)&hsh[pb * 264 + cj0] = H0;
      *(uint4*)&hsh[pb * 264 + cj0 + 8] = H1;
    }
    asm volatile("s_waitcnt lgkmcnt(0)" ::: "memory");
    __builtin_amdgcn_s_barrier();               // B1: h parked (covers x-park too)

    // 7. h-part MFMA (two chains)
    {
      const u16* hr = &hsh[(l & 15) * 264 + (l >> 4) * 8];
      const u16* wr = wl + (size_t)(w * 16 + (l & 15)) * 392 + 128 + (l >> 4) * 8;
#pragma unroll
      for (int kb = 0; kb < 8; kb += 2) {
        acc0 = MFMA(*(const short8*)(hr + 32 * kb), *(const short8*)(wr + 32 * kb),
                    acc0, 0, 0, 0);
        acc1 = MFMA(*(const short8*)(hr + 32 * (kb + 1)), *(const short8*)(wr + 32 * (kb + 1)),
                    acc1, 0, 0, 0);
      }
    }
    acc0 = acc0 + acc1;
    // 8. gates -> per-wave slab: ALL 64 lanes write their 4 C/D rows
    //    (m = (l>>4)*4 + reg covers batches 0..15; r10's `if(l<32)` guard
    //    dropped rows 8-15 -> the absmax 0.949 failure)
    {
      int n = l & 15;
      int m0 = (l >> 4) * 4;
      glw[(m0 + 0) * 20 + n] = acc0[0]; glw[(m0 + 1) * 20 + n] = acc0[1];
      glw[(m0 + 2) * 20 + n] = acc0[2]; glw[(m0 + 3) * 20 + n] = acc0[3];
    }
    asm volatile("s_waitcnt lgkmcnt(0)" ::: "memory");  // wave-local write->read

    // 9. elementwise (wave w handles its own 4 j-slots x 16 batches)
    {
      f32x4 g4 = *(const f32x4*)&glw[eb * 20 + ejl * 4];
      float ii = sigm(g4[0]), ff = sigm(g4[1]);
      float gg = tanh_fast(g4[2]), oo = sigm(g4[3]);
      float c = ff * c_reg + ii * gg;
      c_reg = c;
      float h = oo * tanh_fast(c);
      u32 msg = ((u32)((s + 2) & 0xffff) << 16) | f2bf(h);
      __hip_atomic_store(hbuf + (((size_t)(sw * 8 + grp)) * 16 + eb) * 256 + jglob,
                         msg, __ATOMIC_RELAXED, __HIP_MEMORY_SCOPE_AGENT);
      out[((size_t)t * NB + b0 + eb) * (2 * HID) + d * HID + jglob] = h;
      if (s == 1023) {
        out[TAIL_H + ((size_t)d * NB + b0 + eb) * HID + jglob] = h;
        out[TAIL_C + ((size_t)d * NB + b0 + eb) * HID + jglob] = c;
      }
    }
    __builtin_amdgcn_s_barrier();               // B2: hsh/gl/xsh[p] free for next step
  }
}

extern "C" void kernel_launch(void* const* d_in, const int* in_sizes, int n_in,
                              void* d_out, int out_size, void* d_ws, size_t ws_size,
                              hipStream_t stream) {
  const float* x     = (const float*)d_in[0];
  const float* hx    = (const float*)d_in[1];
  const float* cx    = (const float*)d_in[2];
  const float* Wih_f = (const float*)d_in[3];
  const float* Whh_f = (const float*)d_in[4];
  const float* bih_f = (const float*)d_in[5];
  const float* bhh_f = (const float*)d_in[6];
  const float* Wih_r = (const float*)d_in[7];
  const float* Whh_r = (const float*)d_in[8];
  const float* bih_r = (const float*)d_in[9];
  const float* bhh_r = (const float*)d_in[10];
  float* out = (float*)d_out;

  u16* Wg      = (u16*)((char*)d_ws + WG_OFF);
  float* bias4 = (float*)((char*)d_ws + BIAS_OFF);
  u16* xb      = (u16*)((char*)d_ws + XB_OFF);
  u32* hbuf    = (u32*)((char*)d_ws + HB_OFF);

  // 86,016 B dynamic LDS: two WGs can never share a CU.
  hipFuncSetAttribute((const void*)lstm_tag4,
                      hipFuncAttributeMaxDynamicSharedMemorySize, 86016);

  hipLaunchKernelGGL(prep_kernel, dim3(2048), dim3(256), 0, stream,
                     x, Wih_f, Whh_f, bih_f, bhh_f, Wih_r, Whh_r, bih_r, bhh_r,
                     hx, Wg, bias4, xb, hbuf);
  hipLaunchKernelGGL(lstm_tag4, dim3(128), dim3(256), 86016, stream,
                     Wg, bias4, xb, cx, hbuf, out);
}

// Round 12
// 2236.001 us; speedup vs baseline: 1.8899x; 1.8899x over previous
//
#include <hip/hip_runtime.h>
#include <cstddef>

#define T_STEPS 1024
#define NB      64
#define DIN     128
#define HID     256
#define WPG     16

typedef unsigned short u16;
typedef unsigned int   u32;
typedef unsigned long long u64;
typedef __attribute__((ext_vector_type(8))) short short8;
typedef __attribute__((ext_vector_type(4))) float f32x4;
typedef __attribute__((ext_vector_type(4))) unsigned int u32x4;

// ws byte offsets
#define WG_OFF   0u          // bf16 weights [2][1024 rows j*4+q][384 k] = 1,572,864 B
#define BIAS_OFF 1572864u    // f32 [2][1024]
#define XB_OFF   1581056u    // bf16 x [1024][64][128] = 16,777,216 B
#define HB_OFF   18358272u   // u16 hbuf [2 par][8 grp][16 b][256 j] = 131,072 B
#define FL_OFF   18489344u   // u32 flags [8 grp][1024 steps] = 32,768 B
#define TST_OFF  18522112u   // u32 tst [128][16] = 8,192 B (coherence probe)
#define PRE_OFF  18530304u   // u32 pre [8][8] = 256 B (preamble barriers)
#define OKK_OFF  18530560u   // u32 okk [8][16] = 512 B (per-WG votes)
#define FF_OFF   18531072u   // u32 ff  [8][16] = 512 B (fast flag lines)

#define OUT_MAIN (T_STEPS * NB * 2 * HID)
#define TAIL_H   OUT_MAIN
#define TAIL_C   (OUT_MAIN + 2 * NB * HID)

__device__ __forceinline__ u16 f2bf(float f) {
  unsigned u = __float_as_uint(f);
  return (u16)((u + 0x7fffu + ((u >> 16) & 1u)) >> 16);  // RNE
}
__device__ __forceinline__ float sigm(float v) { return 1.f / (1.f + __expf(-v)); }
__device__ __forceinline__ float tanh_fast(float x) {
  float e = __expf(-2.f * fabsf(x));
  float r = (1.f - e) / (1.f + e);
  return x < 0.f ? -r : r;
}
// L1-bypassing (L2-coherent) loads
__device__ __forceinline__ u32 ld_sc0(const u32* p) {
  u32 v;
  asm volatile("global_load_dword %0, %1, off sc0\n\ts_waitcnt vmcnt(0)"
               : "=&v"(v) : "v"(p) : "memory");
  return v;
}

__global__ void prep_kernel(const float* __restrict__ x,
                            const float* __restrict__ Wih_f, const float* __restrict__ Whh_f,
                            const float* __restrict__ bih_f, const float* __restrict__ bhh_f,
                            const float* __restrict__ Wih_r, const float* __restrict__ Whh_r,
                            const float* __restrict__ bih_r, const float* __restrict__ bhh_r,
                            const float* __restrict__ hx,
                            u16* __restrict__ Wg, float* __restrict__ bias4,
                            u16* __restrict__ xb, u16* __restrict__ hbuf,
                            u32* __restrict__ flags, u32* __restrict__ aux) {
  // segments: W 786432 | bias 2048 | xb 8388608 | hx-cells 32768 | flags 8192 | aux 2368
  const int total = 786432 + 2048 + 8388608 + 32768 + 8192 + 2368;
  for (int i = blockIdx.x * blockDim.x + threadIdx.x; i < total;
       i += gridDim.x * blockDim.x) {
    if (i < 786432) {
      int d = i / 393216;
      int r = i - d * 393216;
      int rowg = r / 384, k = r - rowg * 384;   // rowg = j*4+q interleaved
      int j = rowg >> 2, q = rowg & 3;
      int g = q * HID + j;                      // torch gate row
      const float* Wih = d ? Wih_r : Wih_f;
      const float* Whh = d ? Whh_r : Whh_f;
      float v = (k < DIN) ? Wih[g * DIN + k] : Whh[g * HID + (k - DIN)];
      Wg[i] = f2bf(v);
    } else if (i < 786432 + 2048) {
      int r = i - 786432;
      int d = r >> 10, rowg = r & 1023;
      int j = rowg >> 2, q = rowg & 3;
      int g = q * HID + j;
      bias4[r] = d ? (bih_r[g] + bhh_r[g]) : (bih_f[g] + bhh_f[g]);
    } else if (i < 786432 + 2048 + 8388608) {
      int r = i - (786432 + 2048);
      xb[r] = f2bf(x[r]);                       // [t][b][k]
    } else if (i < 786432 + 2048 + 8388608 + 32768) {
      int r = i - (786432 + 2048 + 8388608);    // (d*64+b)*256 + j
      int d = r >> 14, b = (r >> 8) & 63, j = r & 255;
      int grp = d * 4 + (b >> 4), bb = b & 15;
      hbuf[((size_t)(8 + grp) * 16 + bb) * 256 + j] = f2bf(hx[r]);  // parity 1
      hbuf[((size_t)(0 + grp) * 16 + bb) * 256 + j] = 0;            // parity 0
    } else if (i < 786432 + 2048 + 8388608 + 32768 + 8192) {
      int r = i - (786432 + 2048 + 8388608 + 32768);  // g*1024 + s
      flags[r] = ((r & 1023) == 0) ? (u32)WPG : 0u;   // step 0 pre-released
    } else {
      aux[i - (786432 + 2048 + 8388608 + 32768 + 8192)] = 0u;  // tst|pre|okk|ff
    }
  }
}

#define MFMA __builtin_amdgcn_mfma_f32_16x16x32_bf16
#define ALD64(P) __hip_atomic_load((P), __ATOMIC_RELAXED, __HIP_MEMORY_SCOPE_AGENT)

// 128 WGs x 256 thr. grp = bid&7 (16 WGs co-XCD under round-robin dispatch),
// jsl = bid>>3. grp = d*4 + btile. Per WG: 64 gate rows, 16 batches.
// Weights in LDS. Exchange: r9 flag protocol; if the runtime coherence probe
// proves the group's 16 WGs share one XCD L2, swap the agent-scope (LLC)
// primitives for plain-store + sc0-load (L2) ones -- ~2.5x lower RT.
__global__ __launch_bounds__(256, 1) void lstm_hyb(
    const u16* __restrict__ Wg, const float* __restrict__ bias4,
    const u16* __restrict__ xb, const float* __restrict__ cx,
    u16* __restrict__ hbuf, u32* __restrict__ flags,
    u32* __restrict__ tst, u32* __restrict__ pre,
    u32* __restrict__ okk, u32* __restrict__ ff,
    float* __restrict__ out) {
  extern __shared__ char smem[];
  u16* wl   = (u16*)smem;                 // [64][392]    50,176 B
  u16* xsh  = (u16*)(smem + 50176);       // [2][16][136]  8,704 B
  u16* hsh  = (u16*)(smem + 58880);       // [16][264]     8,448 B
  float* gl = (float*)(smem + 67328);     // [16][68]      4,352 B  (tot 71,680)

  const int tid = threadIdx.x;
  const int bid = blockIdx.x;
  const int grp = bid & 7;
  const int jsl = bid >> 3;
  const int d = grp >> 2, b0 = (grp & 3) * 16;
  const int w = tid >> 6, l = tid & 63;

  // ---- preamble: prove (or refute) group-wide L2 coherence ----
  int fast;
  {
    volatile int* lflag = (volatile int*)gl;
    if (tid == 0) lflag[0] = 0;
    __syncthreads();
    for (int rnd = 0; rnd < 2; ++rnd) {
      u32 base = 0xA5000000u + (u32)rnd * 0x01000000u;
      if (tid < 16) tst[bid * 16 + tid] = base ^ (u32)(bid * 131 + tid * 7);
      asm volatile("s_waitcnt vmcnt(0)" ::: "memory");
      __syncthreads();
      if (tid == 0) {   // agent barrier: all writes of this round done
        __hip_atomic_fetch_add(pre + grp * 8 + rnd, 1u, __ATOMIC_RELAXED, __HIP_MEMORY_SCOPE_AGENT);
        while (__hip_atomic_load(pre + grp * 8 + rnd, __ATOMIC_RELAXED, __HIP_MEMORY_SCOPE_AGENT) < WPG)
          __builtin_amdgcn_s_sleep(1);
      }
      __syncthreads();
      {
        int peer = tid >> 4, word = tid & 15;
        int pbid = peer * 8 + grp;
        u32 v = ld_sc0(tst + pbid * 16 + word);
        if (v != (base ^ (u32)(pbid * 131 + word * 7))) lflag[0] = 1;
      }
      __syncthreads();
      if (tid == 0) {   // agent barrier: all reads done before next-round writes
        __hip_atomic_fetch_add(pre + grp * 8 + 2 + rnd, 1u, __ATOMIC_RELAXED, __HIP_MEMORY_SCOPE_AGENT);
        while (__hip_atomic_load(pre + grp * 8 + 2 + rnd, __ATOMIC_RELAXED, __HIP_MEMORY_SCOPE_AGENT) < WPG)
          __builtin_amdgcn_s_sleep(1);
      }
      __syncthreads();
    }
    if (tid == 0) {
      __hip_atomic_store(okk + grp * 16 + jsl, lflag[0] ? 1u : 2u,
                         __ATOMIC_RELAXED, __HIP_MEMORY_SCOPE_AGENT);
      asm volatile("s_waitcnt vmcnt(0)" ::: "memory");
      __hip_atomic_fetch_add(pre + grp * 8 + 4, 1u, __ATOMIC_RELAXED, __HIP_MEMORY_SCOPE_AGENT);
      while (__hip_atomic_load(pre + grp * 8 + 4, __ATOMIC_RELAXED, __HIP_MEMORY_SCOPE_AGENT) < WPG)
        __builtin_amdgcn_s_sleep(1);
      u32 all2 = 1;
      for (int i2 = 0; i2 < 16; ++i2)
        if (__hip_atomic_load(okk + grp * 16 + i2, __ATOMIC_RELAXED, __HIP_MEMORY_SCOPE_AGENT) != 2u)
          all2 = 0;
      lflag[1] = (int)all2;
    }
    __syncthreads();
    fast = lflag[1];
    __syncthreads();
  }

  // one-time: weight slice -> LDS (dword stride 196, balanced banking)
  {
    const u32* src = (const u32*)(Wg + (size_t)(d * 1024 + jsl * 64) * 384);
    u32* dst = (u32*)wl;
    for (int iu = tid; iu < 64 * 192; iu += 256) {
      int r = iu / 192, c = iu - r * 192;
      dst[r * 196 + c] = src[iu];
    }
  }
  const float bv = bias4[d * 1024 + jsl * 64 + w * 16 + (l & 15)];

  // elementwise identity: eb = batch, ej = local j
  const int eb = tid >> 4, ej = tid & 15;
  const int jglob = jsl * 16 + ej;
  float c_reg = cx[((size_t)d * NB + b0 + eb) * HID + jglob];

  const int xr_row = tid >> 4;            // x stage row (16 batches)
  const int xc = (tid & 15) * 8;          // 8 u16 = 16 B per thread
  const int pb = tid >> 4;                // h consumer batch
  const int cj0 = (tid & 15) * 16;        // 16 h cells per thread

  // prologue: stage x(t0), prefetch x(t1), issue h(init) loads (parity 1, agent)
  { int t0 = d ? 1023 : 0;
    *(uint4*)&xsh[(0 * 16 + xr_row) * 136 + xc] =
        *(const uint4*)&xb[((size_t)t0 * NB + b0 + xr_row) * DIN + xc]; }
  uint4 xv;
  { int t1 = d ? 1022 : 1;
    xv = *(const uint4*)&xb[((size_t)t1 * NB + b0 + xr_row) * DIN + xc]; }
  u64 h0, h1, h2, h3;
  { const u64* hp = (const u64*)(hbuf + ((size_t)(8 + grp) * 16 + pb) * 256 + cj0);
    h0 = ALD64(hp + 0); h1 = ALD64(hp + 1); h2 = ALD64(hp + 2); h3 = ALD64(hp + 3); }
  __syncthreads();

  for (int s = 0; s < T_STEPS; ++s) {
    const int p = s & 1;
    const int t = d ? (1023 - s) : s;

    // park x(s+1) into the other buffer
    if (s < 1023) *(uint4*)&xsh[((p ^ 1) * 16 + xr_row) * 136 + xc] = xv;

    // x-part MFMA (hides in-flight h loads)
    f32x4 acc = {bv, bv, bv, bv};
    {
      const u16* xr = &xsh[(p * 16 + (l & 15)) * 136 + (l >> 4) * 8];
      const u16* wr = wl + (size_t)(w * 16 + (l & 15)) * 392 + (l >> 4) * 8;
      acc = MFMA(*(const short8*)(xr + 0),  *(const short8*)(wr + 0),  acc, 0, 0, 0);
      acc = MFMA(*(const short8*)(xr + 32), *(const short8*)(wr + 32), acc, 0, 0, 0);
      acc = MFMA(*(const short8*)(xr + 64), *(const short8*)(wr + 64), acc, 0, 0, 0);
      acc = MFMA(*(const short8*)(xr + 96), *(const short8*)(wr + 96), acc, 0, 0, 0);
    }
    // park h (waits vmcnt on h regs only)
    {
      uint4 H0, H1;
      H0.x = (u32)h0; H0.y = (u32)(h0 >> 32); H0.z = (u32)h1; H0.w = (u32)(h1 >> 32);
      H1.x = (u32)h2; H1.y = (u32)(h2 >> 32); H1.z = (u32)h3; H1.w = (u32)(h3 >> 32);
      *(uint4*)&hsh[pb * 264 + cj0] = H0;
      *(uint4*)&hsh[pb * 264 + cj0 + 8] = H1;
    }
    asm volatile("s_waitcnt lgkmcnt(0)" ::: "memory");
    __builtin_amdgcn_s_barrier();                // B1: h parked

    // h-part MFMA
    {
      const u16* hr = &hsh[(l & 15) * 264 + (l >> 4) * 8];
      const u16* wr = wl + (size_t)(w * 16 + (l & 15)) * 392 + 128 + (l >> 4) * 8;
#pragma unroll
      for (int kb = 0; kb < 8; ++kb)
        acc = MFMA(*(const short8*)(hr + 32 * kb), *(const short8*)(wr + 32 * kb),
                   acc, 0, 0, 0);
    }
    {
      int n = w * 16 + (l & 15);
      int m0 = (l >> 4) * 4;
      gl[(m0 + 0) * 68 + n] = acc[0]; gl[(m0 + 1) * 68 + n] = acc[1];
      gl[(m0 + 2) * 68 + n] = acc[2]; gl[(m0 + 3) * 68 + n] = acc[3];
    }
    asm volatile("s_waitcnt lgkmcnt(0)" ::: "memory");
    __builtin_amdgcn_s_barrier();                // B2: gates published

    // elementwise (all 256 threads) + h publish
    f32x4 g4 = *(const f32x4*)&gl[eb * 68 + 4 * ej];
    float ii = sigm(g4[0]), ffg = sigm(g4[1]);
    float gg = tanh_fast(g4[2]), oo = sigm(g4[3]);
    float c = ffg * c_reg + ii * gg;
    c_reg = c;
    float h = oo * tanh_fast(c);
    u16 hb16 = f2bf(h);
    {
      u16* hp = hbuf + ((size_t)(p * 8 + grp) * 16 + eb) * 256 + jglob;
      if (fast) *hp = hb16;                      // plain store -> local L2
      else __hip_atomic_store(hp, hb16, __ATOMIC_RELAXED, __HIP_MEMORY_SCOPE_AGENT);
    }
    asm volatile("s_waitcnt vmcnt(0)" ::: "memory");   // h visible (L2 or LLC)
    __builtin_amdgcn_s_barrier();                // B3: all h stores drained
    if (tid == 0 && s < 1023) {
      if (fast) ff[grp * 16 + jsl] = (u32)(s + 1);      // plain flag store
      else __hip_atomic_fetch_add(flags + grp * 1024 + (s + 1), 1u,
                                  __ATOMIC_RELAXED, __HIP_MEMORY_SCOPE_AGENT);
    }
    // fire-and-forget stores after the flag
    out[((size_t)t * NB + b0 + eb) * (2 * HID) + d * HID + jglob] = h;
    if (s == 1023) {
      out[TAIL_H + ((size_t)d * NB + b0 + eb) * HID + jglob] = h;
      out[TAIL_C + ((size_t)d * NB + b0 + eb) * HID + jglob] = c;
    }
    // x prefetch for s+2
    if (s < 1022) {
      int tn = d ? (1021 - s) : (s + 2);
      xv = *(const uint4*)&xb[((size_t)tn * NB + b0 + xr_row) * DIN + xc];
    }
    if (s < 1023) {
      if (tid == 0) {
        const u32 wantv = (u32)(s + 1);
        if (fast) {
          const u32* fl = ff + grp * 16;
          while (1) {
            u32x4 a, b, c2, d2;
            asm volatile(
                "global_load_dwordx4 %0, %4, off sc0\n\t"
                "global_load_dwordx4 %1, %4, off offset:16 sc0\n\t"
                "global_load_dwordx4 %2, %4, off offset:32 sc0\n\t"
                "global_load_dwordx4 %3, %4, off offset:48 sc0\n\t"
                "s_waitcnt vmcnt(0)"
                : "=&v"(a), "=&v"(b), "=&v"(c2), "=&v"(d2)
                : "v"(fl) : "memory");
            u32 mn = a[0];
#pragma unroll
            for (int q2 = 1; q2 < 4; ++q2) mn = mn < a[q2] ? mn : a[q2];
#pragma unroll
            for (int q2 = 0; q2 < 4; ++q2) { mn = mn < b[q2] ? mn : b[q2];
              mn = mn < c2[q2] ? mn : c2[q2]; mn = mn < d2[q2] ? mn : d2[q2]; }
            if (mn >= wantv) break;
          }
        } else {
          const u32* fp = flags + grp * 1024 + (s + 1);
          while (__hip_atomic_load(fp, __ATOMIC_RELAXED, __HIP_MEMORY_SCOPE_AGENT) < WPG)
            __builtin_amdgcn_s_sleep(1);
        }
      }
      __builtin_amdgcn_s_barrier();              // B4: group released
      // issue h(s) loads (parity p)
      if (fast) {
        const u16* hp = hbuf + ((size_t)(p * 8 + grp) * 16 + pb) * 256 + cj0;
        u32x4 lo, hi;
        asm volatile(
            "global_load_dwordx4 %0, %2, off sc0\n\t"
            "global_load_dwordx4 %1, %2, off offset:16 sc0\n\t"
            "s_waitcnt vmcnt(0)"
            : "=&v"(lo), "=&v"(hi) : "v"(hp) : "memory");
        h0 = (u64)lo[0] | ((u64)lo[1] << 32);
        h1 = (u64)lo[2] | ((u64)lo[3] << 32);
        h2 = (u64)hi[0] | ((u64)hi[1] << 32);
        h3 = (u64)hi[2] | ((u64)hi[3] << 32);
      } else {
        const u64* hp = (const u64*)(hbuf + ((size_t)(p * 8 + grp) * 16 + pb) * 256 + cj0);
        h0 = ALD64(hp + 0); h1 = ALD64(hp + 1); h2 = ALD64(hp + 2); h3 = ALD64(hp + 3);
      }
    }
  }
}

extern "C" void kernel_launch(void* const* d_in, const int* in_sizes, int n_in,
                              void* d_out, int out_size, void* d_ws, size_t ws_size,
                              hipStream_t stream) {
  const float* x     = (const float*)d_in[0];
  const float* hx    = (const float*)d_in[1];
  const float* cx    = (const float*)d_in[2];
  const float* Wih_f = (const float*)d_in[3];
  const float* Whh_f = (const float*)d_in[4];
  const float* bih_f = (const float*)d_in[5];
  const float* bhh_f = (const float*)d_in[6];
  const float* Wih_r = (const float*)d_in[7];
  const float* Whh_r = (const float*)d_in[8];
  const float* bih_r = (const float*)d_in[9];
  const float* bhh_r = (const float*)d_in[10];
  float* out = (float*)d_out;

  u16* Wg      = (u16*)((char*)d_ws + WG_OFF);
  float* bias4 = (float*)((char*)d_ws + BIAS_OFF);
  u16* xb      = (u16*)((char*)d_ws + XB_OFF);
  u16* hbuf    = (u16*)((char*)d_ws + HB_OFF);
  u32* flags   = (u32*)((char*)d_ws + FL_OFF);
  u32* tst     = (u32*)((char*)d_ws + TST_OFF);
  u32* pre     = (u32*)((char*)d_ws + PRE_OFF);
  u32* okk     = (u32*)((char*)d_ws + OKK_OFF);
  u32* ff      = (u32*)((char*)d_ws + FF_OFF);

  // 86,016 B dynamic LDS: two WGs can never share a CU.
  hipFuncSetAttribute((const void*)lstm_hyb,
                      hipFuncAttributeMaxDynamicSharedMemorySize, 86016);

  hipLaunchKernelGGL(prep_kernel, dim3(2048), dim3(256), 0, stream,
                     x, Wih_f, Whh_f, bih_f, bhh_f, Wih_r, Whh_r, bih_r, bhh_r,
                     hx, Wg, bias4, xb, hbuf, flags, tst);
  hipLaunchKernelGGL(lstm_hyb, dim3(128), dim3(256), 86016, stream,
                     Wg, bias4, xb, cx, hbuf, flags, tst, pre, okk, ff, out);
}